// Round 7
// baseline (341.291 us; speedup 1.0000x reference)
//
#include <hip/hip_runtime.h>
#include <stdint.h>

typedef __attribute__((ext_vector_type(8))) short short8;
typedef __attribute__((ext_vector_type(4))) float f32x4;
typedef unsigned short ushort_t;

// fp32 -> bf16 round-to-nearest-even
__device__ __forceinline__ ushort_t f2bf(float f) {
  uint32_t u = __float_as_uint(f);
  u += 0x7fffu + ((u >> 16) & 1u);
  return (ushort_t)(u >> 16);
}

__device__ __forceinline__ uint2 pack4(float4 v) {
  return make_uint2((uint32_t)f2bf(v.x) | ((uint32_t)f2bf(v.y) << 16),
                    (uint32_t)f2bf(v.z) | ((uint32_t)f2bf(v.w) << 16));
}

// async global->LDS, 16B per lane; LDS dest = wave-uniform base + lane*16
__device__ __forceinline__ void load_lds16(const ushort_t* g, ushort_t* l) {
  __builtin_amdgcn_global_load_lds(
      (const __attribute__((address_space(1))) uint32_t*)g,
      (__attribute__((address_space(3))) uint32_t*)l, 16, 0, 0);
}

// Single-use grid barrier: counter pre-zeroed by hipMemsetAsync. Monotonic
// targets (512, 1024) reuse one counter. Device-scope fences per G16.
__device__ __forceinline__ void grid_barrier(unsigned* cnt, unsigned target) {
  __syncthreads();
  __threadfence();  // release prior writes, device scope
  if (threadIdx.x == 0) {
    atomicAdd(cnt, 1u);  // device-scope by default on gfx950
    while (__hip_atomic_load(cnt, __ATOMIC_RELAXED,
                             __HIP_MEMORY_SCOPE_AGENT) < target) {
      __builtin_amdgcn_s_sleep(2);
    }
  }
  __syncthreads();
  __threadfence();  // acquire side
}

// One dispatch, 512 blocks x 256 threads, co-resident by construction
// (48 KB LDS -> 3 blocks/CU; launch_bounds caps VGPR at 128).
// P1: rows -> dis, Abf = bf16(dis[n]*(A+I))          (row scale folded)
// B1
// P2: HLt[b][o][m] = bf16((W@H^T + bias) * dis[m])   (col scale folded)
// B2
// P3: out[b][n][o] = relu(mask[n] * Abf @ HLt^T)
__global__ __launch_bounds__(256, 4) void k_all(
    const float* __restrict__ W,     // [256][256] fp32
    const float* __restrict__ H,     // [32][512][256] fp32
    const float* __restrict__ bias,  // [256]
    const float* __restrict__ mask,  // [32*512]
    const float* __restrict__ A,     // [32][512][512] fp32
    ushort_t* __restrict__ Abf,      // ws [32][512][512] bf16
    ushort_t* __restrict__ HLt,      // ws [32][256][512] bf16
    float* __restrict__ dis,         // ws [32*512]
    unsigned* __restrict__ cnt,      // ws barrier counter (pre-zeroed)
    float* __restrict__ out) {       // [32][512][256] fp32
  __shared__ ushort_t smem[24576];  // 48 KB, reused across phases
  const int bid = blockIdx.x;
  const int tid = threadIdx.x, lane = tid & 63, wv = tid >> 6;
  const int lr = lane & 15, q = lane >> 4;

  // ---- P1: 32 rows per block; rowsum + dis + row-scaled bf16 convert ----
  {
    const float4* A4 = (const float4*)A;
    const int row0 = bid * 32 + wv * 8;
#pragma unroll
    for (int i = 0; i < 8; ++i) {
      const int row = row0 + i;
      const int n = row & 511;
      const float4* src = A4 + (size_t)row * 128;
      uint2* dst = (uint2*)(Abf + (size_t)row * 512);
      float4 v0 = src[lane], v1 = src[64 + lane];
      const int c0 = lane * 4, c1 = 256 + lane * 4;
      v0.x += (float)(c0 == n);  // identity fold
      v0.y += (float)(c0 + 1 == n);
      v0.z += (float)(c0 + 2 == n);
      v0.w += (float)(c0 + 3 == n);
      v1.x += (float)(c1 == n);
      v1.y += (float)(c1 + 1 == n);
      v1.z += (float)(c1 + 2 == n);
      v1.w += (float)(c1 + 3 == n);
      float s = (v0.x + v0.y) + (v0.z + v0.w) + (v1.x + v1.y) + (v1.z + v1.w);
#pragma unroll
      for (int off = 32; off > 0; off >>= 1) s += __shfl_xor(s, off, 64);
      const float d = rsqrtf(s + 1e-8f);  // all lanes have it
      v0.x *= d; v0.y *= d; v0.z *= d; v0.w *= d;
      v1.x *= d; v1.y *= d; v1.z *= d; v1.w *= d;
      dst[lane] = pack4(v0);
      dst[64 + lane] = pack4(v1);
      if (lane == 0) dis[row] = d;
    }
  }

  grid_barrier(cnt, 512);  // dis complete & visible

  // ---- P2: HL GEMM tile 64(o) x 128(m), K=256, BK=32, fp32 inline cvt ----
  {
    ushort_t* As1 = smem;         // [2][64*32]
    ushort_t* Bs1 = smem + 4096;  // [2][128*32]
    const int yo = bid >> 7, rr = bid & 127;
    const int batch = rr >> 2, xm = rr & 3;
    const int ot0 = yo * 64, mt0 = xm * 128;
    const int wo = wv & 1, wmh = wv >> 1;
    const float* Hb = H + (size_t)batch * 512 * 256;
    const int a_r = tid >> 2, a_kc = (tid & 3) * 8;
    const int b_r = tid >> 1, b_kc = (tid & 1) * 16;

    f32x4 acc[2][4];
#pragma unroll
    for (int i = 0; i < 2; ++i)
#pragma unroll
      for (int j = 0; j < 4; ++j) acc[i][j] = {0.f, 0.f, 0.f, 0.f};

    float4 ra[2], rb[4];
    auto gload = [&](int k0) {
      const float* wp = W + (size_t)(ot0 + a_r) * 256 + k0 + a_kc;
      ra[0] = *(const float4*)wp;
      ra[1] = *(const float4*)(wp + 4);
      const float* hp = Hb + (size_t)(mt0 + b_r) * 256 + k0 + b_kc;
#pragma unroll
      for (int j = 0; j < 4; ++j) rb[j] = *(const float4*)(hp + 4 * j);
    };
    auto stash = [&](int p) {
      uint2 a0 = pack4(ra[0]), a1 = pack4(ra[1]);
      *(uint4*)&As1[p * 2048 + a_r * 32 + a_kc] =
          make_uint4(a0.x, a0.y, a1.x, a1.y);
      uint2 b0 = pack4(rb[0]), b1 = pack4(rb[1]);
      uint2 b2 = pack4(rb[2]), b3 = pack4(rb[3]);
      *(uint4*)&Bs1[p * 4096 + b_r * 32 + b_kc] =
          make_uint4(b0.x, b0.y, b1.x, b1.y);
      *(uint4*)&Bs1[p * 4096 + b_r * 32 + b_kc + 8] =
          make_uint4(b2.x, b2.y, b3.x, b3.y);
    };
    auto compute = [&](int p) {
      short8 af[2], bfr[4];
#pragma unroll
      for (int mt = 0; mt < 2; ++mt)
        af[mt] = *(const short8*)&As1[p * 2048 +
                                      (wo * 32 + mt * 16 + lr) * 32 + q * 8];
#pragma unroll
      for (int nt = 0; nt < 4; ++nt)
        bfr[nt] = *(const short8*)&Bs1[p * 4096 +
                                       (wmh * 64 + nt * 16 + lr) * 32 + q * 8];
#pragma unroll
      for (int mt = 0; mt < 2; ++mt)
#pragma unroll
        for (int nt = 0; nt < 4; ++nt)
          acc[mt][nt] = __builtin_amdgcn_mfma_f32_16x16x32_bf16(
              af[mt], bfr[nt], acc[mt][nt], 0, 0, 0);
    };

    gload(0);
#pragma unroll
    for (int it = 0; it < 8; ++it) {
      stash(it & 1);
      __syncthreads();
      if (it + 1 < 8) gload((it + 1) * 32);
      compute(it & 1);
    }

    float dm[4];
#pragma unroll
    for (int nt = 0; nt < 4; ++nt)
      dm[nt] = dis[batch * 512 + mt0 + wmh * 64 + nt * 16 + lr];
#pragma unroll
    for (int mt = 0; mt < 2; ++mt) {
      const int ob = ot0 + wo * 32 + mt * 16 + q * 4;
      float bs[4];
#pragma unroll
      for (int r = 0; r < 4; ++r) bs[r] = bias[ob + r];
#pragma unroll
      for (int nt = 0; nt < 4; ++nt) {
        const int m = mt0 + wmh * 64 + nt * 16 + lr;
        ushort_t* dstp = HLt + ((size_t)batch * 256 + ob) * 512 + m;
#pragma unroll
        for (int r = 0; r < 4; ++r)
          dstp[(size_t)r * 512] = f2bf((acc[mt][nt][r] + bs[r]) * dm[nt]);
      }
    }
  }

  grid_barrier(cnt, 1024);  // Abf + HLt complete & visible

  // ---- P3: out GEMM tile 64(n) x 128(o), K=512, BK=64 (2x32 slabs) -------
  {
    ushort_t* As2 = smem;         // [4][64*32] slab slots
    ushort_t* Bs2 = smem + 8192;  // [4][128*32]
    const int yo = bid >> 8, rem = bid & 255;
    const int batch = rem >> 3, xn = rem & 7;
    const int nt0 = xn * 64, ot0 = yo * 128;
    const int wn2 = wv & 1, wo2 = wv >> 1;
    const int rstage = lane >> 2, koff = (lane & 3) * 8;
    const ushort_t* Ab = Abf + (size_t)batch * 512 * 512;
    const ushort_t* Gb = HLt + (size_t)batch * 256 * 512;

    f32x4 acc[2][4];
#pragma unroll
    for (int i = 0; i < 2; ++i)
#pragma unroll
      for (int j = 0; j < 4; ++j) acc[i][j] = {0.f, 0.f, 0.f, 0.f};

    auto stage = [&](int k0, int slot) {
      load_lds16(Ab + (size_t)(nt0 + wv * 16 + rstage) * 512 + k0 + koff,
                 &As2[slot * 2048 + wv * 512]);
#pragma unroll
      for (int j = 0; j < 2; ++j) {
        const int c = wv * 2 + j;
        load_lds16(Gb + (size_t)(ot0 + c * 16 + rstage) * 512 + k0 + koff,
                   &Bs2[slot * 4096 + c * 512]);
      }
    };
    auto compute = [&](int slot) {
      short8 af[2], bfr[4];
#pragma unroll
      for (int mt = 0; mt < 2; ++mt)
        af[mt] = *(const short8*)&As2[slot * 2048 +
                                      (wn2 * 32 + mt * 16 + lr) * 32 + q * 8];
#pragma unroll
      for (int nt = 0; nt < 4; ++nt)
        bfr[nt] = *(const short8*)&Bs2[slot * 4096 +
                                       (wo2 * 64 + nt * 16 + lr) * 32 + q * 8];
#pragma unroll
      for (int mt = 0; mt < 2; ++mt)
#pragma unroll
        for (int nt = 0; nt < 4; ++nt)
          acc[mt][nt] = __builtin_amdgcn_mfma_f32_16x16x32_bf16(
              af[mt], bfr[nt], acc[mt][nt], 0, 0, 0);
    };

    stage(0, 0);
    stage(32, 1);
#pragma unroll
    for (int it = 0; it < 8; ++it) {  // BK=64 per iteration
      __syncthreads();
      if (it + 1 < 8) {
        const int base = ((it + 1) & 1) * 2, k0 = (it + 1) * 64;
        stage(k0, base);
        stage(k0 + 32, base + 1);
      }
      const int cb = (it & 1) * 2;
      compute(cb);
      compute(cb + 1);
    }

#pragma unroll
    for (int mt = 0; mt < 2; ++mt) {
      const int nb = nt0 + wn2 * 32 + mt * 16 + q * 4;
      float sc[4];
#pragma unroll
      for (int r = 0; r < 4; ++r) sc[r] = mask[batch * 512 + nb + r];
#pragma unroll
      for (int nt = 0; nt < 4; ++nt) {
        const int o = ot0 + wo2 * 64 + nt * 16 + lr;
        float* dstp = out + ((size_t)(batch * 512 + nb)) * 256 + o;
#pragma unroll
        for (int r = 0; r < 4; ++r) {
          float v = acc[mt][nt][r] * sc[r];
          dstp[(size_t)r * 256] = v > 0.0f ? v : 0.0f;
        }
      }
    }
  }
}

extern "C" void kernel_launch(void* const* d_in, const int* in_sizes, int n_in,
                              void* d_out, int out_size, void* d_ws,
                              size_t ws_size, hipStream_t stream) {
  const float* H = (const float*)d_in[0];     // [32][512][256]
  const float* A = (const float*)d_in[1];     // [32][512][512]
  const float* mask = (const float*)d_in[2];  // [32][512]
  const float* W = (const float*)d_in[3];     // [256][256]
  const float* b = (const float*)d_in[4];     // [256]
  float* out = (float*)d_out;                 // [32][512][256]

  char* ws = (char*)d_ws;
  ushort_t* Abf = (ushort_t*)ws;               // 16 MiB
  ushort_t* HLt = (ushort_t*)(ws + 16777216);  // 8 MiB
  float* dis = (float*)(ws + 25165824);        // 64 KiB
  unsigned* cnt = (unsigned*)(ws + 25231360);  // barrier counter

  hipMemsetAsync(cnt, 0, 64, stream);  // zero the barrier counter (capture-ok)
  k_all<<<512, 256, 0, stream>>>(W, H, b, mask, A, Abf, HLt, dis, cnt, out);
}